// Round 1
// baseline (2941.422 us; speedup 1.0000x reference)
//
#include <hip/hip_runtime.h>
#include <math.h>

#define IDIM 1771
#define NB 256
#define NF 64
#define NG 512

constexpr int OFFS[11] = {0, 1, 10, 35, 84, 165, 286, 455, 680, 969, 1330};

// ---------------------------------------------------------------------------
// Kernel 1: psi[io][c] = (1/sqrt(512)) * sum_n D[n][c] * w[io][n]
// block = 256 threads (one c each), 16 io per block.
// D loads coalesced across lanes (consecutive c); w loads wave-uniform -> SMEM.
// ---------------------------------------------------------------------------
__global__ __launch_bounds__(256) void psi_kernel(const float* __restrict__ D,
                                                  const float* __restrict__ w,
                                                  float* __restrict__ psi) {
    const int t = threadIdx.x;
    const int c = blockIdx.x * 256 + t;
    const int io0 = blockIdx.y * 16;
    const int cc = (c < IDIM) ? c : (IDIM - 1);

    float acc[16];
#pragma unroll
    for (int j = 0; j < 16; ++j) acc[j] = 0.0f;

    const float* wp = w + io0 * NG;
#pragma unroll 4
    for (int n = 0; n < NG; ++n) {
        float dv = D[n * IDIM + cc];
#pragma unroll
        for (int j = 0; j < 16; ++j) acc[j] += dv * wp[j * NG + n];
    }

    if (c < IDIM) {
        const float s = 0.04419417382415922f;  // 1/sqrt(512)
#pragma unroll
        for (int j = 0; j < 16; ++j) psi[(io0 + j) * IDIM + c] = acc[j] * s;
    }
}

// ---------------------------------------------------------------------------
// Kernel 2 (per l): out[b,o,off+v*d+m] = alpha * sum_{i,u} x[b,i,off+u*d+m] *
//                                                 psi[i,o,off+u*d+v]
// GEMM view: C[(b,m),(o,v)] = A[(b,m),(i,u)] * W[(i,u),(o,v)]
//   M' = 256*d (divisible by 128 tile -> no row guards)
//   N' = 64*d  (ragged vs 128 -> col guards)
//   K' = 64*d  (divisible by 16)
// 256 threads, 128x128 tile, 8x8 accum per thread, KT=16.
// ---------------------------------------------------------------------------
template <int L>
__global__ __launch_bounds__(256) void so3_kernel(const float* __restrict__ x,
                                                  const float* __restrict__ psi,
                                                  float* __restrict__ out) {
    constexpr int d = 2 * L + 1;
    constexpr int off = OFFS[L];
    constexpr int Np = 64 * d;
    constexpr int Kp = 64 * d;

    const int row0 = blockIdx.x * 128;  // over M' = 256*d
    const int col0 = blockIdx.y * 128;  // over N' = 64*d

    __shared__ float As[16][128];
    __shared__ float Bs[16][128];

    const int t = threadIdx.x;
    const int tx = t & 15;   // col group 0..15
    const int ty = t >> 4;   // row group 0..15

    float acc[8][8];
#pragma unroll
    for (int jr = 0; jr < 8; ++jr)
#pragma unroll
        for (int jc = 0; jc < 8; ++jc) acc[jr][jc] = 0.0f;

    // A staging: element (rA, k = kt + p*2 + kA0), p = 0..7
    const int rA = t & 127;
    const int kA0 = t >> 7;  // 0/1
    const int rg = row0 + rA;
    const int bA = rg / d, mA = rg % d;
    const float* xbase = x + bA * (NF * IDIM) + off + mA;

    // B staging: element (qB, k = kt + p*2 + kB0), p = 0..7
    const int qB = t & 127;
    const int kB0 = t >> 7;  // 0/1
    const int qg = col0 + qB;
    const bool qok = (qg < Np);
    const int oB = qok ? qg / d : 0;
    const int vB = qok ? qg % d : 0;
    const float* pbase = psi + oB * IDIM + off + vB;

    for (int kt = 0; kt < Kp; kt += 16) {
        __syncthreads();
#pragma unroll
        for (int p = 0; p < 8; ++p) {
            int k = kt + p * 2 + kA0;
            int i = k / d, u = k % d;
            As[p * 2 + kA0][rA] = xbase[i * IDIM + u * d];
        }
#pragma unroll
        for (int p = 0; p < 8; ++p) {
            int k = kt + p * 2 + kB0;
            int i = k / d, u = k % d;
            Bs[p * 2 + kB0][qB] = qok ? pbase[i * (NF * IDIM) + u * d] : 0.0f;
        }
        __syncthreads();
#pragma unroll
        for (int k = 0; k < 16; ++k) {
            float a[8], b[8];
#pragma unroll
            for (int j = 0; j < 8; ++j) a[j] = As[k][ty * 8 + j];
#pragma unroll
            for (int j = 0; j < 4; ++j) {
                b[j] = Bs[k][tx * 4 + j];
                b[4 + j] = Bs[k][64 + tx * 4 + j];
            }
#pragma unroll
            for (int jr = 0; jr < 8; ++jr)
#pragma unroll
                for (int jc = 0; jc < 8; ++jc) acc[jr][jc] += a[jr] * b[jc];
        }
    }

    const float alpha = 1.0f / sqrtf(64.0f * d);
#pragma unroll
    for (int jr = 0; jr < 8; ++jr) {
        int r = row0 + ty * 8 + jr;
        int bb = r / d, m = r % d;
        int obase = bb * (NF * IDIM) + off + m;
#pragma unroll
        for (int jc = 0; jc < 8; ++jc) {
            int q = col0 + ((jc < 4) ? (tx * 4 + jc) : (64 + tx * 4 + jc - 4));
            if (q < Np) {
                int o = q / d, v = q % d;
                out[obase + o * IDIM + v * d] = acc[jr][jc] * alpha;
            }
        }
    }
}

// ---------------------------------------------------------------------------
extern "C" void kernel_launch(void* const* d_in, const int* in_sizes, int n_in,
                              void* d_out, int out_size, void* d_ws, size_t ws_size,
                              hipStream_t stream) {
    const float* x = (const float*)d_in[0];   // (256, 64, 1771)
    const float* D = (const float*)d_in[1];   // (512, 1771)
    const float* w = (const float*)d_in[2];   // (64, 64, 512)
    float* out = (float*)d_out;               // (256, 64, 1771)
    float* psi = (float*)d_ws;                // (64, 64, 1771) = 29.0 MB fp32

    // Stage 1: psi
    psi_kernel<<<dim3(7, 256), 256, 0, stream>>>(D, w, psi);

    // Stage 2: per-l block GEMMs. grid = (M'/128, ceil(N'/128)) = (2d, (d+1)/2)
    so3_kernel<0><<<dim3(2, 1), 256, 0, stream>>>(x, psi, out);
    so3_kernel<1><<<dim3(6, 2), 256, 0, stream>>>(x, psi, out);
    so3_kernel<2><<<dim3(10, 3), 256, 0, stream>>>(x, psi, out);
    so3_kernel<3><<<dim3(14, 4), 256, 0, stream>>>(x, psi, out);
    so3_kernel<4><<<dim3(18, 5), 256, 0, stream>>>(x, psi, out);
    so3_kernel<5><<<dim3(22, 6), 256, 0, stream>>>(x, psi, out);
    so3_kernel<6><<<dim3(26, 7), 256, 0, stream>>>(x, psi, out);
    so3_kernel<7><<<dim3(30, 8), 256, 0, stream>>>(x, psi, out);
    so3_kernel<8><<<dim3(34, 9), 256, 0, stream>>>(x, psi, out);
    so3_kernel<9><<<dim3(38, 10), 256, 0, stream>>>(x, psi, out);
    so3_kernel<10><<<dim3(42, 11), 256, 0, stream>>>(x, psi, out);
}

// Round 3
// 751.578 us; speedup vs baseline: 3.9137x; 3.9137x over previous
//
#include <hip/hip_runtime.h>
#include <hip/hip_bf16.h>
#include <math.h>

#define IDIM 1771
#define NF 64
#define NG 512

constexpr int OFFS[12] = {0, 1, 10, 35, 84, 165, 286, 455, 680, 969, 1330, 1771};

typedef float f32x4 __attribute__((ext_vector_type(4)));
typedef __bf16 bf16x8 __attribute__((ext_vector_type(8)));

__device__ __forceinline__ void gl_lds16(const void* g, void* l) {
    __builtin_amdgcn_global_load_lds((const __attribute__((address_space(1))) void*)g,
                                     (__attribute__((address_space(3))) void*)l, 16, 0, 0);
}

// ---------------------------------------------------------------------------
// Stage 1: psi[i][o][c] = (1/sqrt(512)) * sum_n D[n][c] * w[i][o][n]
// ---------------------------------------------------------------------------
__global__ __launch_bounds__(256) void psi_kernel(const float* __restrict__ D,
                                                  const float* __restrict__ w,
                                                  float* __restrict__ psi) {
    const int t = threadIdx.x;
    const int c = blockIdx.x * 256 + t;
    const int io0 = blockIdx.y * 16;
    const int cc = (c < IDIM) ? c : (IDIM - 1);

    float acc[16];
#pragma unroll
    for (int j = 0; j < 16; ++j) acc[j] = 0.0f;

    const float* wp = w + io0 * NG;
#pragma unroll 4
    for (int n = 0; n < NG; ++n) {
        float dv = D[n * IDIM + cc];
#pragma unroll
        for (int j = 0; j < 16; ++j) acc[j] += dv * wp[j * NG + n];
    }

    if (c < IDIM) {
        const float s = 0.04419417382415922f;  // 1/sqrt(512)
#pragma unroll
        for (int j = 0; j < 16; ++j) psi[(io0 + j) * IDIM + c] = acc[j] * s;
    }
}

// ---------------------------------------------------------------------------
// Repack x -> A_l[M'=256d][K'=64d] bf16, row r=b*d+m, col k=u*64+i.
// A_l base offset = 16384*OFFS[l] elements.
// ---------------------------------------------------------------------------
__global__ __launch_bounds__(256) void repack_x_kernel(const float* __restrict__ x,
                                                       __hip_bfloat16* __restrict__ A) {
    const int b = blockIdx.x;
    const int l = blockIdx.y;
    const int d = 2 * l + 1, off = OFFS[l], csq = d * d, Kp = 64 * d;
    __shared__ __hip_bfloat16 T[64][66];  // [i][c], pad 2 -> 2-way-max aliasing
    const int t = threadIdx.x, lane = t & 63, grp = t >> 6;
    const float* xb = x + (size_t)b * NF * IDIM + off;
    __hip_bfloat16* Ab = A + (size_t)16384 * off + (size_t)b * d * Kp;

    for (int c0 = 0; c0 < csq; c0 += 64) {
        for (int ii = grp; ii < 64; ii += 4) {
            int c = c0 + lane;
            float v = (c < csq) ? xb[ii * IDIM + c] : 0.0f;
            T[ii][lane] = __float2bfloat16(v);
        }
        __syncthreads();
        for (int cc = grp; cc < 64; cc += 4) {
            int c = c0 + cc;
            if (c < csq) {
                int u = c / d, m = c - u * d;
                Ab[(size_t)m * Kp + u * 64 + lane] = T[lane][cc];
            }
        }
        __syncthreads();
    }
}

// ---------------------------------------------------------------------------
// Repack psi -> B_l[N'=64d][K'=64d] bf16, row q=o*d+v, col k=u*64+i.
// B_l base offset = 4096*OFFS[l] elements.
// ---------------------------------------------------------------------------
__global__ __launch_bounds__(256) void repack_psi_kernel(const float* __restrict__ psi,
                                                         __hip_bfloat16* __restrict__ Bm) {
    const int o = blockIdx.x;  // 0..63
    const int l = blockIdx.y;
    const int d = 2 * l + 1, off = OFFS[l], csq = d * d, Kp = 64 * d;
    __shared__ __hip_bfloat16 T[64][66];
    const int t = threadIdx.x, lane = t & 63, grp = t >> 6;
    const float* pb = psi + (size_t)o * IDIM + off;  // + i*64*IDIM
    __hip_bfloat16* Bb = Bm + (size_t)4096 * off + (size_t)o * d * Kp;

    for (int c0 = 0; c0 < csq; c0 += 64) {
        for (int ii = grp; ii < 64; ii += 4) {
            int c = c0 + lane;
            float v = (c < csq) ? pb[(size_t)ii * NF * IDIM + c] : 0.0f;
            T[ii][lane] = __float2bfloat16(v);
        }
        __syncthreads();
        for (int cc = grp; cc < 64; cc += 4) {
            int c = c0 + cc;
            if (c < csq) {
                int u = c / d, vv = c - u * d;
                Bb[(size_t)vv * Kp + u * 64 + lane] = T[lane][cc];
            }
        }
        __syncthreads();
    }
}

// ---------------------------------------------------------------------------
// Per-l MFMA GEMM: C[r][q] = sum_k A_l[r][k]*B_l[q][k]  (NT, K-contiguous)
// 128x128 tile, BK=32, 4 waves, each wave 4x4 grid of 16x16x32 bf16 MFMA.
// ---------------------------------------------------------------------------
template <int L>
__global__ __launch_bounds__(256) void so3_mfma_kernel(const __bf16* __restrict__ A,
                                                       const __bf16* __restrict__ Bm,
                                                       float* __restrict__ out) {
    constexpr int d = 2 * L + 1;
    constexpr int off = OFFS[L];
    constexpr int Np = 64 * d;
    constexpr int Kp = 64 * d;

    __shared__ alignas(16) __bf16 As[128 * 32];
    __shared__ alignas(16) __bf16 Bs[128 * 32];

    const int t = threadIdx.x, w = t >> 6, ln = t & 63;
    const int row0 = blockIdx.x * 128, col0 = blockIdx.y * 128;

    // FIX (R2 bug): per-l base offsets were missing -> l>=1 read wrong data.
    const __bf16* Abase = A + (size_t)16384 * off;
    const __bf16* Bbase = Bm + (size_t)4096 * off;

    // staging: 16 chunks of 1KB (16 rows x 64B); chunk = w*4+q; 0..7 -> A, 8..15 -> B
    const __bf16* gp[4];
    __bf16* lp[4];
#pragma unroll
    for (int q = 0; q < 4; ++q) {
        int chunk = w * 4 + q;
        bool isA = chunk < 8;
        int j = isA ? chunk : chunk - 8;
        int r16 = j * 16 + (ln >> 2);
        int g = isA ? (row0 + r16) : (col0 + r16 < Np ? col0 + r16 : Np - 1);
        gp[q] = (isA ? Abase : Bbase) + (size_t)g * Kp + (ln & 3) * 8;
        lp[q] = (isA ? As : Bs) + j * 512;
    }

    f32x4 acc[4][4];
    f32x4 zero = {0.0f, 0.0f, 0.0f, 0.0f};
#pragma unroll
    for (int i = 0; i < 4; ++i)
#pragma unroll
        for (int j = 0; j < 4; ++j) acc[i][j] = zero;

    const int wr = (w >> 1) * 64, wc = (w & 1) * 64;
    const int fr = ln & 15, kh = ln >> 4;

    for (int kt = 0; kt < Kp; kt += 32) {
        __syncthreads();
#pragma unroll
        for (int q = 0; q < 4; ++q) {
            gl_lds16(gp[q], lp[q]);
            gp[q] += 32;
        }
        __syncthreads();

        bf16x8 af[4], bfr[4];
#pragma unroll
        for (int mt = 0; mt < 4; ++mt)
            af[mt] = *(const bf16x8*)&As[(wr + mt * 16 + fr) * 32 + kh * 8];
#pragma unroll
        for (int nt = 0; nt < 4; ++nt)
            bfr[nt] = *(const bf16x8*)&Bs[(wc + nt * 16 + fr) * 32 + kh * 8];
#pragma unroll
        for (int mt = 0; mt < 4; ++mt)
#pragma unroll
            for (int nt = 0; nt < 4; ++nt)
                acc[mt][nt] = __builtin_amdgcn_mfma_f32_16x16x32_bf16(af[mt], bfr[nt],
                                                                      acc[mt][nt], 0, 0, 0);
    }

    const float alpha = 1.0f / sqrtf(64.0f * (float)d);
#pragma unroll
    for (int mt = 0; mt < 4; ++mt) {
#pragma unroll
        for (int e = 0; e < 4; ++e) {
            int r = row0 + wr + mt * 16 + kh * 4 + e;
            int b = r / d, m = r - b * d;
            float* ob = out + (size_t)b * NF * IDIM + off + m;
#pragma unroll
            for (int nt = 0; nt < 4; ++nt) {
                int q = col0 + wc + nt * 16 + fr;
                if (q < Np) {
                    int o = q / d, v = q - o * d;
                    ob[o * IDIM + v * d] = alpha * acc[mt][nt][e];
                }
            }
        }
    }
}

// ---------------------------------------------------------------------------
// Fallback (round-1 fp32 path) in case ws_size < 102MB.
// ---------------------------------------------------------------------------
template <int L>
__global__ __launch_bounds__(256) void so3_fp32_kernel(const float* __restrict__ x,
                                                       const float* __restrict__ psi,
                                                       float* __restrict__ out) {
    constexpr int d = 2 * L + 1;
    constexpr int off = OFFS[L];
    constexpr int Np = 64 * d;
    constexpr int Kp = 64 * d;

    const int row0 = blockIdx.x * 128;
    const int col0 = blockIdx.y * 128;

    __shared__ float Asf[16][128];
    __shared__ float Bsf[16][128];

    const int t = threadIdx.x;
    const int tx = t & 15;
    const int ty = t >> 4;

    float acc[8][8];
#pragma unroll
    for (int jr = 0; jr < 8; ++jr)
#pragma unroll
        for (int jc = 0; jc < 8; ++jc) acc[jr][jc] = 0.0f;

    const int rA = t & 127;
    const int kA0 = t >> 7;
    const int rg = row0 + rA;
    const int bA = rg / d, mA = rg % d;
    const float* xbase = x + bA * (NF * IDIM) + off + mA;

    const int qB = t & 127;
    const int kB0 = t >> 7;
    const int qg = col0 + qB;
    const bool qok = (qg < Np);
    const int oB = qok ? qg / d : 0;
    const int vB = qok ? qg % d : 0;
    const float* pbase = psi + oB * IDIM + off + vB;

    for (int kt = 0; kt < Kp; kt += 16) {
        __syncthreads();
#pragma unroll
        for (int p = 0; p < 8; ++p) {
            int k = kt + p * 2 + kA0;
            int i = k / d, u = k % d;
            Asf[p * 2 + kA0][rA] = xbase[i * IDIM + u * d];
        }
#pragma unroll
        for (int p = 0; p < 8; ++p) {
            int k = kt + p * 2 + kB0;
            int i = k / d, u = k % d;
            Bsf[p * 2 + kB0][qB] = qok ? pbase[i * (NF * IDIM) + u * d] : 0.0f;
        }
        __syncthreads();
#pragma unroll
        for (int k = 0; k < 16; ++k) {
            float a[8], bb[8];
#pragma unroll
            for (int j = 0; j < 8; ++j) a[j] = Asf[k][ty * 8 + j];
#pragma unroll
            for (int j = 0; j < 4; ++j) {
                bb[j] = Bsf[k][tx * 4 + j];
                bb[4 + j] = Bsf[k][64 + tx * 4 + j];
            }
#pragma unroll
            for (int jr = 0; jr < 8; ++jr)
#pragma unroll
                for (int jc = 0; jc < 8; ++jc) acc[jr][jc] += a[jr] * bb[jc];
        }
    }

    const float alpha = 1.0f / sqrtf(64.0f * d);
#pragma unroll
    for (int jr = 0; jr < 8; ++jr) {
        int r = row0 + ty * 8 + jr;
        int bb2 = r / d, m = r % d;
        int obase = bb2 * (NF * IDIM) + off + m;
#pragma unroll
        for (int jc = 0; jc < 8; ++jc) {
            int q = col0 + ((jc < 4) ? (tx * 4 + jc) : (64 + tx * 4 + jc - 4));
            if (q < Np) {
                int o = q / d, v = q % d;
                out[obase + o * IDIM + v * d] = acc[jr][jc] * alpha;
            }
        }
    }
}

// ---------------------------------------------------------------------------
extern "C" void kernel_launch(void* const* d_in, const int* in_sizes, int n_in,
                              void* d_out, int out_size, void* d_ws, size_t ws_size,
                              hipStream_t stream) {
    const float* x = (const float*)d_in[0];   // (256, 64, 1771)
    const float* D = (const float*)d_in[1];   // (512, 1771)
    const float* w = (const float*)d_in[2];   // (64, 64, 512)
    float* out = (float*)d_out;               // (256, 64, 1771)

    char* ws = (char*)d_ws;
    const size_t PSI_BYTES = (size_t)4096 * IDIM * 4;   // 29,016,064
    const size_t A_BYTES = (size_t)16384 * IDIM * 2;    // 58,032,128
    const size_t B_BYTES = (size_t)4096 * IDIM * 2;     // 14,508,032

    float* psi = (float*)ws;
    __hip_bfloat16* A = (__hip_bfloat16*)(ws + PSI_BYTES);
    __hip_bfloat16* Bm = (__hip_bfloat16*)(ws + PSI_BYTES + A_BYTES);

    psi_kernel<<<dim3(7, 256), 256, 0, stream>>>(D, w, psi);

    if (ws_size >= PSI_BYTES + A_BYTES + B_BYTES) {
        repack_x_kernel<<<dim3(256, 11), 256, 0, stream>>>(x, A);
        repack_psi_kernel<<<dim3(64, 11), 256, 0, stream>>>(psi, Bm);

        const __bf16* Ab = (const __bf16*)A;
        const __bf16* Bb = (const __bf16*)Bm;
        so3_mfma_kernel<0><<<dim3(2, 1), 256, 0, stream>>>(Ab, Bb, out);
        so3_mfma_kernel<1><<<dim3(6, 2), 256, 0, stream>>>(Ab, Bb, out);
        so3_mfma_kernel<2><<<dim3(10, 3), 256, 0, stream>>>(Ab, Bb, out);
        so3_mfma_kernel<3><<<dim3(14, 4), 256, 0, stream>>>(Ab, Bb, out);
        so3_mfma_kernel<4><<<dim3(18, 5), 256, 0, stream>>>(Ab, Bb, out);
        so3_mfma_kernel<5><<<dim3(22, 6), 256, 0, stream>>>(Ab, Bb, out);
        so3_mfma_kernel<6><<<dim3(26, 7), 256, 0, stream>>>(Ab, Bb, out);
        so3_mfma_kernel<7><<<dim3(30, 8), 256, 0, stream>>>(Ab, Bb, out);
        so3_mfma_kernel<8><<<dim3(34, 9), 256, 0, stream>>>(Ab, Bb, out);
        so3_mfma_kernel<9><<<dim3(38, 10), 256, 0, stream>>>(Ab, Bb, out);
        so3_mfma_kernel<10><<<dim3(42, 11), 256, 0, stream>>>(Ab, Bb, out);
    } else {
        so3_fp32_kernel<0><<<dim3(2, 1), 256, 0, stream>>>(x, psi, out);
        so3_fp32_kernel<1><<<dim3(6, 2), 256, 0, stream>>>(x, psi, out);
        so3_fp32_kernel<2><<<dim3(10, 3), 256, 0, stream>>>(x, psi, out);
        so3_fp32_kernel<3><<<dim3(14, 4), 256, 0, stream>>>(x, psi, out);
        so3_fp32_kernel<4><<<dim3(18, 5), 256, 0, stream>>>(x, psi, out);
        so3_fp32_kernel<5><<<dim3(22, 6), 256, 0, stream>>>(x, psi, out);
        so3_fp32_kernel<6><<<dim3(26, 7), 256, 0, stream>>>(x, psi, out);
        so3_fp32_kernel<7><<<dim3(30, 8), 256, 0, stream>>>(x, psi, out);
        so3_fp32_kernel<8><<<dim3(34, 9), 256, 0, stream>>>(x, psi, out);
        so3_fp32_kernel<9><<<dim3(38, 10), 256, 0, stream>>>(x, psi, out);
        so3_fp32_kernel<10><<<dim3(42, 11), 256, 0, stream>>>(x, psi, out);
    }
}

// Round 4
// 477.139 us; speedup vs baseline: 6.1647x; 1.5752x over previous
//
#include <hip/hip_runtime.h>
#include <hip/hip_bf16.h>

#define IDIM 1771
#define NF 64
#define NG 512

constexpr int OFFS[12] = {0, 1, 10, 35, 84, 165, 286, 455, 680, 969, 1330, 1771};

typedef float f32x4 __attribute__((ext_vector_type(4)));
typedef __bf16 bf16x4 __attribute__((ext_vector_type(4)));
typedef __bf16 bf16x8 __attribute__((ext_vector_type(8)));

__device__ __forceinline__ void gl_lds16(const void* g, void* l) {
    __builtin_amdgcn_global_load_lds((const __attribute__((address_space(1))) void*)g,
                                     (__attribute__((address_space(3))) void*)l, 16, 0, 0);
}

// ---------------------------------------------------------------------------
// Prep: blocks 0..223 transpose D (512,1771) fp32 -> Dt (1771,512) bf16;
//       blocks 224..287 cast w (64,64,512) fp32 -> wb bf16 (same layout).
// ---------------------------------------------------------------------------
__global__ __launch_bounds__(256) void prep_kernel(const float* __restrict__ D,
                                                   const float* __restrict__ w,
                                                   __bf16* __restrict__ Dt,
                                                   __bf16* __restrict__ wb) {
    const int blk = blockIdx.x;
    const int t = threadIdx.x;
    if (blk < 224) {
        const int ct = blk >> 3, nt = blk & 7;
        const int c0 = ct * 64, n0 = nt * 64;
        __shared__ float T[64][65];
        const int lane = t & 63, grp = t >> 6;
        for (int nn = grp; nn < 64; nn += 4) {
            int c = c0 + lane;
            T[nn][lane] = (c < IDIM) ? D[(n0 + nn) * IDIM + c] : 0.0f;
        }
        __syncthreads();
        for (int cc = grp; cc < 64; cc += 4) {
            int c = c0 + cc;
            if (c < IDIM) Dt[c * NG + n0 + lane] = (__bf16)T[lane][cc];
        }
    } else {
        const int b = blk - 224;  // 0..63, each covers 32768 elems
#pragma unroll 4
        for (int it = 0; it < 32; ++it) {
            int idx = b * 32768 + it * 1024 + t * 4;
            f32x4 v = *(const f32x4*)&w[idx];
            bf16x4 o;
            o.x = (__bf16)v.x; o.y = (__bf16)v.y; o.z = (__bf16)v.z; o.w = (__bf16)v.w;
            *(bf16x4*)&wb[idx] = o;
        }
    }
}

// ---------------------------------------------------------------------------
// psi GEMM (MFMA): C[c][io] = (1/sqrt512) * sum_n Dt[c][n] * wb[io][n]
// M=1771 (14 tiles), N=4096 (32 tiles), K=512. Epilogue scatters bf16
// straight into the stage-2 B_l layout: Bm[4096*off + (o*d+v)*64d + u*64 + i]
// where c = off + u*d + v, io = i*64 + o.
// ---------------------------------------------------------------------------
__global__ __launch_bounds__(256) void psi_mfma_kernel(const __bf16* __restrict__ Dt,
                                                       const __bf16* __restrict__ wb,
                                                       __bf16* __restrict__ Bm) {
    __shared__ alignas(16) __bf16 As[128 * 32];
    __shared__ alignas(16) __bf16 Bs[128 * 32];

    const int t = threadIdx.x, w = t >> 6, ln = t & 63;
    const int row0 = blockIdx.x * 128;  // c
    const int col0 = blockIdx.y * 128;  // io

    const __bf16* gp[4];
    __bf16* lp[4];
#pragma unroll
    for (int q = 0; q < 4; ++q) {
        int chunk = w * 4 + q;
        bool isA = chunk < 8;
        int j = isA ? chunk : chunk - 8;
        int r16 = j * 16 + (ln >> 2);
        int g = isA ? (row0 + r16 < IDIM ? row0 + r16 : IDIM - 1) : (col0 + r16);
        gp[q] = (isA ? Dt : wb) + (size_t)g * NG + (ln & 3) * 8;
        lp[q] = (isA ? As : Bs) + j * 512;
    }

    f32x4 acc[4][4];
    f32x4 zero = {0.0f, 0.0f, 0.0f, 0.0f};
#pragma unroll
    for (int i = 0; i < 4; ++i)
#pragma unroll
        for (int j = 0; j < 4; ++j) acc[i][j] = zero;

    const int wr = (w >> 1) * 64, wc = (w & 1) * 64;
    const int fr = ln & 15, kh = ln >> 4;

    for (int kt = 0; kt < NG; kt += 32) {
        __syncthreads();
#pragma unroll
        for (int q = 0; q < 4; ++q) {
            gl_lds16(gp[q], lp[q]);
            gp[q] += 32;
        }
        __syncthreads();

        bf16x8 af[4], bfr[4];
#pragma unroll
        for (int mt = 0; mt < 4; ++mt)
            af[mt] = *(const bf16x8*)&As[(wr + mt * 16 + fr) * 32 + kh * 8];
#pragma unroll
        for (int nt = 0; nt < 4; ++nt)
            bfr[nt] = *(const bf16x8*)&Bs[(wc + nt * 16 + fr) * 32 + kh * 8];
#pragma unroll
        for (int mt = 0; mt < 4; ++mt)
#pragma unroll
            for (int nt = 0; nt < 4; ++nt)
                acc[mt][nt] = __builtin_amdgcn_mfma_f32_16x16x32_bf16(af[mt], bfr[nt],
                                                                      acc[mt][nt], 0, 0, 0);
    }

    const float s = 0.04419417382415922f;  // 1/sqrt(512)
#pragma unroll
    for (int mt = 0; mt < 4; ++mt) {
#pragma unroll
        for (int e = 0; e < 4; ++e) {
            int c = row0 + wr + mt * 16 + kh * 4 + e;
            if (c < IDIM) {
                int l = 0;
#pragma unroll
                for (int ll = 1; ll < 11; ++ll)
                    if (c >= OFFS[ll]) l = ll;
                int d = 2 * l + 1, off = OFFS[l];
                int rem = c - off;
                int u = (unsigned)rem / (unsigned)d;
                int v = rem - u * d;
                __bf16* bb = Bm + (size_t)4096 * off + u * 64;
#pragma unroll
                for (int nt = 0; nt < 4; ++nt) {
                    int io = col0 + wc + nt * 16 + fr;
                    int i = io >> 6, o = io & 63;
                    bb[(size_t)(o * d + v) * (64 * d) + i] = (__bf16)(acc[mt][nt][e] * s);
                }
            }
        }
    }
}

// ---------------------------------------------------------------------------
// Repack x -> A_l[M'=256d][K'=64d] bf16, row r=b*d+m, col k=u*64+i.
// A_l base offset = 16384*OFFS[l] elements.
// ---------------------------------------------------------------------------
__global__ __launch_bounds__(256) void repack_x_kernel(const float* __restrict__ x,
                                                       __hip_bfloat16* __restrict__ A) {
    const int b = blockIdx.x;
    const int l = blockIdx.y;
    const int d = 2 * l + 1, off = OFFS[l], csq = d * d, Kp = 64 * d;
    __shared__ __hip_bfloat16 T[64][66];
    const int t = threadIdx.x, lane = t & 63, grp = t >> 6;
    const float* xb = x + (size_t)b * NF * IDIM + off;
    __hip_bfloat16* Ab = A + (size_t)16384 * off + (size_t)b * d * Kp;

    for (int c0 = 0; c0 < csq; c0 += 64) {
        for (int ii = grp; ii < 64; ii += 4) {
            int c = c0 + lane;
            float v = (c < csq) ? xb[ii * IDIM + c] : 0.0f;
            T[ii][lane] = __float2bfloat16(v);
        }
        __syncthreads();
        for (int cc = grp; cc < 64; cc += 4) {
            int c = c0 + cc;
            if (c < csq) {
                int u = c / d, m = c - u * d;
                Ab[(size_t)m * Kp + u * 64 + lane] = T[lane][cc];
            }
        }
        __syncthreads();
    }
}

// ---------------------------------------------------------------------------
// Merged stage-2 GEMM: one launch, 1892 blocks, longest-l-first.
// Per block: find (l, bx, by), then 128x128 NT MFMA tile with runtime d.
// ---------------------------------------------------------------------------
__global__ __launch_bounds__(256) void so3_gemm_all(const __bf16* __restrict__ A,
                                                    const __bf16* __restrict__ Bm,
                                                    float* __restrict__ out) {
    const int bid = blockIdx.x;
    // segments in descending l: sizes 462,380,306,240,182,132,90,56,30,12,2
    int l = 10, base = 0;
    if (bid >= 462)  { l = 9; base = 462; }
    if (bid >= 842)  { l = 8; base = 842; }
    if (bid >= 1148) { l = 7; base = 1148; }
    if (bid >= 1388) { l = 6; base = 1388; }
    if (bid >= 1570) { l = 5; base = 1570; }
    if (bid >= 1702) { l = 4; base = 1702; }
    if (bid >= 1792) { l = 3; base = 1792; }
    if (bid >= 1848) { l = 2; base = 1848; }
    if (bid >= 1878) { l = 1; base = 1878; }
    if (bid >= 1890) { l = 0; base = 1890; }

    const int d = 2 * l + 1;
    const int off = (l == 0) ? 0 : OFFS[l];  // OFFS indexed by runtime l
    const int Np = 64 * d, Kp = 64 * d;
    const int ntiles = l + 1;  // ceil(d/2)
    const int rel = bid - base;
    const int bx = (unsigned)rel / (unsigned)ntiles;
    const int by = rel - bx * ntiles;
    const int row0 = bx * 128, col0 = by * 128;

    constexpr float ALPHA[11] = {0.125f, 0.07216878f, 0.05590170f, 0.04724556f,
                                 0.04166667f, 0.03768892f, 0.03466879f, 0.03227486f,
                                 0.03031695f, 0.02867697f, 0.02727724f};

    __shared__ alignas(16) __bf16 As[128 * 32];
    __shared__ alignas(16) __bf16 Bs[128 * 32];

    const int t = threadIdx.x, w = t >> 6, ln = t & 63;

    const __bf16* Abase = A + (size_t)16384 * off;
    const __bf16* Bbase = Bm + (size_t)4096 * off;

    const __bf16* gp[4];
    __bf16* lp[4];
#pragma unroll
    for (int q = 0; q < 4; ++q) {
        int chunk = w * 4 + q;
        bool isA = chunk < 8;
        int j = isA ? chunk : chunk - 8;
        int r16 = j * 16 + (ln >> 2);
        int g = isA ? (row0 + r16) : (col0 + r16 < Np ? col0 + r16 : Np - 1);
        gp[q] = (isA ? Abase : Bbase) + (size_t)g * Kp + (ln & 3) * 8;
        lp[q] = (isA ? As : Bs) + j * 512;
    }

    f32x4 acc[4][4];
    f32x4 zero = {0.0f, 0.0f, 0.0f, 0.0f};
#pragma unroll
    for (int i = 0; i < 4; ++i)
#pragma unroll
        for (int j = 0; j < 4; ++j) acc[i][j] = zero;

    const int wr = (w >> 1) * 64, wc = (w & 1) * 64;
    const int fr = ln & 15, kh = ln >> 4;

    for (int kt = 0; kt < Kp; kt += 32) {
        __syncthreads();
#pragma unroll
        for (int q = 0; q < 4; ++q) {
            gl_lds16(gp[q], lp[q]);
            gp[q] += 32;
        }
        __syncthreads();

        bf16x8 af[4], bfr[4];
#pragma unroll
        for (int mt = 0; mt < 4; ++mt)
            af[mt] = *(const bf16x8*)&As[(wr + mt * 16 + fr) * 32 + kh * 8];
#pragma unroll
        for (int nt = 0; nt < 4; ++nt)
            bfr[nt] = *(const bf16x8*)&Bs[(wc + nt * 16 + fr) * 32 + kh * 8];
#pragma unroll
        for (int mt = 0; mt < 4; ++mt)
#pragma unroll
            for (int nt = 0; nt < 4; ++nt)
                acc[mt][nt] = __builtin_amdgcn_mfma_f32_16x16x32_bf16(af[mt], bfr[nt],
                                                                      acc[mt][nt], 0, 0, 0);
    }

    const float alpha = ALPHA[l];
    // per-nt column decomposition (o,v) computed once
    int qo[4], qv[4], qok[4];
#pragma unroll
    for (int nt = 0; nt < 4; ++nt) {
        int q = col0 + wc + nt * 16 + fr;
        qok[nt] = (q < Np);
        int qq = qok[nt] ? q : 0;
        qo[nt] = (unsigned)qq / (unsigned)d;
        qv[nt] = qq - qo[nt] * d;
    }
#pragma unroll
    for (int mt = 0; mt < 4; ++mt) {
#pragma unroll
        for (int e = 0; e < 4; ++e) {
            int r = row0 + wr + mt * 16 + kh * 4 + e;
            int b = (unsigned)r / (unsigned)d, m = r - b * d;
            float* ob = out + (size_t)b * NF * IDIM + off + m;
#pragma unroll
            for (int nt = 0; nt < 4; ++nt) {
                if (qok[nt]) ob[qo[nt] * IDIM + qv[nt] * d] = alpha * acc[mt][nt][e];
            }
        }
    }
}

// ---------------------------------------------------------------------------
extern "C" void kernel_launch(void* const* d_in, const int* in_sizes, int n_in,
                              void* d_out, int out_size, void* d_ws, size_t ws_size,
                              hipStream_t stream) {
    const float* x = (const float*)d_in[0];   // (256, 64, 1771)
    const float* D = (const float*)d_in[1];   // (512, 1771)
    const float* w = (const float*)d_in[2];   // (64, 64, 512)
    float* out = (float*)d_out;               // (256, 64, 1771)

    char* ws = (char*)d_ws;
    const size_t DT_BYTES = (size_t)IDIM * NG * 2;        // 1,813,504
    const size_t WB_BYTES = (size_t)4096 * NG * 2;        // 4,194,304
    const size_t A_BYTES = (size_t)16384 * IDIM * 2;      // 58,032,128
    // Bm: (size_t)4096 * IDIM * 2 = 14,508,032; total 78.5 MB (R3 proved >=101MB avail)

    __bf16* Dt = (__bf16*)ws;
    __bf16* wb = (__bf16*)(ws + DT_BYTES);
    __hip_bfloat16* A = (__hip_bfloat16*)(ws + DT_BYTES + WB_BYTES);
    __bf16* Bm = (__bf16*)(ws + DT_BYTES + WB_BYTES + A_BYTES);

    prep_kernel<<<288, 256, 0, stream>>>(D, w, Dt, wb);
    psi_mfma_kernel<<<dim3(14, 32), 256, 0, stream>>>(Dt, wb, Bm);
    repack_x_kernel<<<dim3(256, 11), 256, 0, stream>>>(x, A);
    so3_gemm_all<<<1892, 256, 0, stream>>>((const __bf16*)A, Bm, out);
}

// Round 5
// 411.941 us; speedup vs baseline: 7.1404x; 1.1583x over previous
//
#include <hip/hip_runtime.h>
#include <hip/hip_bf16.h>

#define IDIM 1771
#define NF 64
#define NG 512

constexpr int OFFS[12] = {0, 1, 10, 35, 84, 165, 286, 455, 680, 969, 1330, 1771};

typedef float f32x4 __attribute__((ext_vector_type(4)));
typedef float f32x2 __attribute__((ext_vector_type(2)));
typedef __bf16 bf16x2 __attribute__((ext_vector_type(2)));
typedef __bf16 bf16x8 __attribute__((ext_vector_type(8)));

__device__ __forceinline__ void gl_lds16(const void* g, void* l) {
    __builtin_amdgcn_global_load_lds((const __attribute__((address_space(1))) void*)g,
                                     (__attribute__((address_space(3))) void*)l, 16, 0, 0);
}

// ---------------------------------------------------------------------------
// Fused prep + repack_x (independent work, one launch):
//  blk 0..223   : transpose D (512,1771) fp32 -> Dt (1771,512) bf16
//  blk 224..287 : transpose-cast w[i][o][n] fp32 -> wb[o][i][n] bf16
//  blk 288..3103: repack x -> A_l[256d][64d] bf16, row r=b*d+m, col k=u*64+i
// ---------------------------------------------------------------------------
__global__ __launch_bounds__(256) void prep_repack_kernel(const float* __restrict__ D,
                                                          const float* __restrict__ w,
                                                          const float* __restrict__ x,
                                                          __bf16* __restrict__ Dt,
                                                          __bf16* __restrict__ wb,
                                                          __hip_bfloat16* __restrict__ A) {
    __shared__ alignas(16) char smem[16640];
    const int blk = blockIdx.x;
    const int t = threadIdx.x;
    const int lane = t & 63, grp = t >> 6;

    if (blk < 224) {
        // D transpose
        float (*T)[65] = (float (*)[65])smem;
        const int ct = blk >> 3, nt = blk & 7;
        const int c0 = ct * 64, n0 = nt * 64;
        for (int nn = grp; nn < 64; nn += 4) {
            int c = c0 + lane;
            T[nn][lane] = (c < IDIM) ? D[(n0 + nn) * IDIM + c] : 0.0f;
        }
        __syncthreads();
        for (int cc = grp; cc < 64; cc += 4) {
            int c = c0 + cc;
            if (c < IDIM) Dt[c * NG + n0 + lane] = (__bf16)T[lane][cc];
        }
    } else if (blk < 288) {
        // w transpose-cast: wb[o][i][n] = bf16(w[i][o][n])
        const int o = blk - 224;
#pragma unroll 4
        for (int ii = 0; ii < 64; ++ii) {
            f32x2 v = *(const f32x2*)&w[((size_t)(ii * 64 + o)) * NG + t * 2];
            bf16x2 ov;
            ov.x = (__bf16)v.x;
            ov.y = (__bf16)v.y;
            *(bf16x2*)&wb[((size_t)(o * 64 + ii)) * NG + t * 2] = ov;
        }
    } else {
        // repack x
        const int idx = blk - 288;
        const int l = idx >> 8;        // 0..10
        const int b = idx & 255;       // 0..255
        const int d = 2 * l + 1, off = OFFS[l], csq = d * d, Kp = 64 * d;
        __hip_bfloat16 (*T)[66] = (__hip_bfloat16 (*)[66])smem;
        const float* xb = x + (size_t)b * NF * IDIM + off;
        __hip_bfloat16* Ab = A + (size_t)16384 * off + (size_t)b * d * Kp;

        for (int c0 = 0; c0 < csq; c0 += 64) {
            for (int ii = grp; ii < 64; ii += 4) {
                int c = c0 + lane;
                float v = (c < csq) ? xb[ii * IDIM + c] : 0.0f;
                T[ii][lane] = __float2bfloat16(v);
            }
            __syncthreads();
            for (int cc = grp; cc < 64; cc += 4) {
                int c = c0 + cc;
                if (c < csq) {
                    int u = c / d, m = c - u * d;
                    Ab[(size_t)m * Kp + u * 64 + lane] = T[lane][cc];
                }
            }
            __syncthreads();
        }
    }
}

// ---------------------------------------------------------------------------
// psi GEMM (MFMA): psi[c][io'] = (1/sqrt512) * sum_n Dt[c][n] * wb[io'][n]
// with io' = o*64 + i (wb transposed in prep). Fragment lanes fr -> consecutive
// i, so the Bm scatter is 32B-contiguous per 16-lane group.
// Bm[4096*off + (o*d+v)*64d + u*64 + i], c = off + u*d + v.
// ---------------------------------------------------------------------------
__global__ __launch_bounds__(256) void psi_mfma_kernel(const __bf16* __restrict__ Dt,
                                                       const __bf16* __restrict__ wb,
                                                       __bf16* __restrict__ Bm) {
    __shared__ alignas(16) __bf16 As[128 * 32];
    __shared__ alignas(16) __bf16 Bs[128 * 32];

    const int t = threadIdx.x, w = t >> 6, ln = t & 63;
    const int row0 = blockIdx.x * 128;  // c
    const int col0 = blockIdx.y * 128;  // io'

    const __bf16* gp[4];
    __bf16* lp[4];
#pragma unroll
    for (int q = 0; q < 4; ++q) {
        int chunk = w * 4 + q;
        bool isA = chunk < 8;
        int j = isA ? chunk : chunk - 8;
        int r16 = j * 16 + (ln >> 2);
        int g = isA ? (row0 + r16 < IDIM ? row0 + r16 : IDIM - 1) : (col0 + r16);
        gp[q] = (isA ? Dt : wb) + (size_t)g * NG + (ln & 3) * 8;
        lp[q] = (isA ? As : Bs) + j * 512;
    }

    f32x4 acc[4][4];
    f32x4 zero = {0.0f, 0.0f, 0.0f, 0.0f};
#pragma unroll
    for (int i = 0; i < 4; ++i)
#pragma unroll
        for (int j = 0; j < 4; ++j) acc[i][j] = zero;

    const int wr = (w >> 1) * 64, wc = (w & 1) * 64;
    const int fr = ln & 15, kh = ln >> 4;

    for (int kt = 0; kt < NG; kt += 32) {
        __syncthreads();
#pragma unroll
        for (int q = 0; q < 4; ++q) {
            gl_lds16(gp[q], lp[q]);
            gp[q] += 32;
        }
        __syncthreads();

        bf16x8 af[4], bfr[4];
#pragma unroll
        for (int mt = 0; mt < 4; ++mt)
            af[mt] = *(const bf16x8*)&As[(wr + mt * 16 + fr) * 32 + kh * 8];
#pragma unroll
        for (int nt = 0; nt < 4; ++nt)
            bfr[nt] = *(const bf16x8*)&Bs[(wc + nt * 16 + fr) * 32 + kh * 8];
#pragma unroll
        for (int mt = 0; mt < 4; ++mt)
#pragma unroll
            for (int nt = 0; nt < 4; ++nt)
                acc[mt][nt] = __builtin_amdgcn_mfma_f32_16x16x32_bf16(af[mt], bfr[nt],
                                                                      acc[mt][nt], 0, 0, 0);
    }

    const float s = 0.04419417382415922f;  // 1/sqrt(512)
    const int o = (col0 + wc) >> 6;        // wave-uniform
#pragma unroll
    for (int mt = 0; mt < 4; ++mt) {
#pragma unroll
        for (int e = 0; e < 4; ++e) {
            int c = row0 + wr + mt * 16 + kh * 4 + e;
            if (c < IDIM) {
                int l = 0;
#pragma unroll
                for (int ll = 1; ll < 11; ++ll)
                    if (c >= OFFS[ll]) l = ll;
                int d = 2 * l + 1, off = OFFS[l];
                int rem = c - off;
                int u = (unsigned)rem / (unsigned)d;
                int v = rem - u * d;
                __bf16* bb = Bm + (size_t)4096 * off + (size_t)(o * d + v) * (64 * d) + u * 64;
#pragma unroll
                for (int nt = 0; nt < 4; ++nt) {
                    int i = nt * 16 + fr;  // consecutive across 16-lane group
                    bb[i] = (__bf16)(acc[mt][nt][e] * s);
                }
            }
        }
    }
}

// ---------------------------------------------------------------------------
// Merged stage-2 GEMM, XCD-swizzled. Epilogue reorders each 16x16 subtile
// through per-wave LDS so global stores are 16-lane contiguous along m.
// ---------------------------------------------------------------------------
__global__ __launch_bounds__(256) void so3_gemm_all(const __bf16* __restrict__ A,
                                                    const __bf16* __restrict__ Bm,
                                                    float* __restrict__ out) {
    // XCD-contiguous swizzle: round-robin bid%8 -> XCD; give each XCD a
    // contiguous virtual-bid range so blocks sharing an A-tile share an L2.
    const int bid = blockIdx.x;
    const int v_ = (bid & 7) * 237 + (bid >> 3);  // grid 1896 = 8*237
    if (v_ >= 1892) return;

    int l = 10, base = 0;
    if (v_ >= 462)  { l = 9; base = 462; }
    if (v_ >= 842)  { l = 8; base = 842; }
    if (v_ >= 1148) { l = 7; base = 1148; }
    if (v_ >= 1388) { l = 6; base = 1388; }
    if (v_ >= 1570) { l = 5; base = 1570; }
    if (v_ >= 1702) { l = 4; base = 1702; }
    if (v_ >= 1792) { l = 3; base = 1792; }
    if (v_ >= 1848) { l = 2; base = 1848; }
    if (v_ >= 1878) { l = 1; base = 1878; }
    if (v_ >= 1890) { l = 0; base = 1890; }

    const int d = 2 * l + 1;
    const int off = OFFS[l];
    const int Np = 64 * d, Kp = 64 * d;
    const int ntiles = l + 1;
    const int rel = v_ - base;
    const int bx = (unsigned)rel / (unsigned)ntiles;
    const int by = rel - bx * ntiles;
    const int row0 = bx * 128, col0 = by * 128;

    constexpr float ALPHA[11] = {0.125f, 0.07216878f, 0.05590170f, 0.04724556f,
                                 0.04166667f, 0.03768892f, 0.03466879f, 0.03227486f,
                                 0.03031695f, 0.02867697f, 0.02727724f};

    __shared__ alignas(16) __bf16 As[128 * 32];
    __shared__ alignas(16) __bf16 Bs[128 * 32];

    const int t = threadIdx.x, w = t >> 6, ln = t & 63;

    const __bf16* Abase = A + (size_t)16384 * off;
    const __bf16* Bbase = Bm + (size_t)4096 * off;

    const __bf16* gp[4];
    __bf16* lp[4];
#pragma unroll
    for (int q = 0; q < 4; ++q) {
        int chunk = w * 4 + q;
        bool isA = chunk < 8;
        int j = isA ? chunk : chunk - 8;
        int r16 = j * 16 + (ln >> 2);
        int g = isA ? (row0 + r16) : (col0 + r16 < Np ? col0 + r16 : Np - 1);
        gp[q] = (isA ? Abase : Bbase) + (size_t)g * Kp + (ln & 3) * 8;
        lp[q] = (isA ? As : Bs) + j * 512;
    }

    f32x4 acc[4][4];
    f32x4 zero = {0.0f, 0.0f, 0.0f, 0.0f};
#pragma unroll
    for (int i = 0; i < 4; ++i)
#pragma unroll
        for (int j = 0; j < 4; ++j) acc[i][j] = zero;

    const int wr = (w >> 1) * 64, wc = (w & 1) * 64;
    const int fr = ln & 15, kh = ln >> 4;

    for (int kt = 0; kt < Kp; kt += 32) {
        __syncthreads();
#pragma unroll
        for (int q = 0; q < 4; ++q) {
            gl_lds16(gp[q], lp[q]);
            gp[q] += 32;
        }
        __syncthreads();

        bf16x8 af[4], bfr[4];
#pragma unroll
        for (int mt = 0; mt < 4; ++mt)
            af[mt] = *(const bf16x8*)&As[(wr + mt * 16 + fr) * 32 + kh * 8];
#pragma unroll
        for (int nt = 0; nt < 4; ++nt)
            bfr[nt] = *(const bf16x8*)&Bs[(wc + nt * 16 + fr) * 32 + kh * 8];
#pragma unroll
        for (int mt = 0; mt < 4; ++mt)
#pragma unroll
            for (int nt = 0; nt < 4; ++nt)
                acc[mt][nt] = __builtin_amdgcn_mfma_f32_16x16x32_bf16(af[mt], bfr[nt],
                                                                      acc[mt][nt], 0, 0, 0);
    }

    // ---- epilogue: per-wave LDS reorder so stores run contiguous along m ----
    __syncthreads();  // all waves done reading As before we reuse it
    float* Tw = (float*)As + w * 256;  // 16x16 f32 per wave (1KB), inside As
    const float alpha = ALPHA[l];

#pragma unroll
    for (int mt = 0; mt < 4; ++mt) {
        // this lane's store row: r = row0+wr+mt*16+fr (contiguous across fr)
        int r = row0 + wr + mt * 16 + fr;
        int b = (unsigned)r / (unsigned)d;
        int m = r - b * d;
        float* ob = out + (size_t)b * NF * IDIM + off + m;
#pragma unroll
        for (int nt = 0; nt < 4; ++nt) {
            // write C subtile (row=kh*4+e, col=fr) into Tw[row][col]
#pragma unroll
            for (int e = 0; e < 4; ++e) Tw[(kh * 4 + e) * 16 + fr] = acc[mt][nt][e];
            // read back transposed: lane handles (row=fr, cols kh*4..kh*4+3)
            f32x4 vals = *(const f32x4*)&Tw[fr * 16 + kh * 4];
            int qb = col0 + wc + nt * 16 + kh * 4;
            int o = (unsigned)qb / (unsigned)d;
            int vv = qb - o * d;
#pragma unroll
            for (int j = 0; j < 4; ++j) {
                if (qb + j < Np) ob[o * IDIM + vv * d] = alpha * vals[j];
                ++vv;
                if (vv == d) { vv = 0; ++o; }
            }
        }
    }
}

// ---------------------------------------------------------------------------
extern "C" void kernel_launch(void* const* d_in, const int* in_sizes, int n_in,
                              void* d_out, int out_size, void* d_ws, size_t ws_size,
                              hipStream_t stream) {
    const float* x = (const float*)d_in[0];   // (256, 64, 1771)
    const float* D = (const float*)d_in[1];   // (512, 1771)
    const float* w = (const float*)d_in[2];   // (64, 64, 512)
    float* out = (float*)d_out;               // (256, 64, 1771)

    char* ws = (char*)d_ws;
    const size_t DT_BYTES = (size_t)IDIM * NG * 2;        // 1,813,504
    const size_t WB_BYTES = (size_t)4096 * NG * 2;        // 4,194,304
    const size_t A_BYTES = (size_t)16384 * IDIM * 2;      // 58,032,128

    __bf16* Dt = (__bf16*)ws;
    __bf16* wb = (__bf16*)(ws + DT_BYTES);
    __hip_bfloat16* A = (__hip_bfloat16*)(ws + DT_BYTES + WB_BYTES);
    __bf16* Bm = (__bf16*)(ws + DT_BYTES + WB_BYTES + A_BYTES);

    prep_repack_kernel<<<3104, 256, 0, stream>>>(D, w, x, Dt, wb, A);
    psi_mfma_kernel<<<dim3(14, 32), 256, 0, stream>>>(Dt, wb, Bm);
    so3_gemm_all<<<1896, 256, 0, stream>>>((const __bf16*)A, Bm, out);
}